// Round 5
// baseline (201.948 us; speedup 1.0000x reference)
//
#include <hip/hip_runtime.h>
#include <stdint.h>

#define NB 32
#define NP 32768
#define NO 32
#define THRESH 0.35f

typedef unsigned long long u64;
typedef unsigned int u32;

// fast IoU from prior corners + truth corners. kern1's additions and kern3's
// delta-subtractions must cancel bit-exactly, so BOTH use this helper.
__device__ __forceinline__ float iou_corners(float px1, float py1, float px2, float py2, float ab,
                                             float tx1, float ty1, float tx2, float ty2, float aa)
{
#pragma clang fp contract(off)
    float iw = fminf(tx2, px2) - fmaxf(tx1, px1);
    float ih = fminf(ty2, py2) - fmaxf(ty1, py1);
    iw = fmaxf(iw, 0.f); ih = fmaxf(ih, 0.f);
    float inter = iw * ih;
    return __fdividef(inter, aa + ab - inter);
}

// smooth-L1 of (loc - encode(truth, prior)), summed over 4 coords
__device__ __forceinline__ float smooth_l1_sum(float4 ld, float4 pr, float4 tt)
{
#pragma clang fp contract(off)
    float g0 = __fdividef((tt.x + tt.z) * 0.5f - pr.x, 0.1f * pr.z);
    float g1 = __fdividef((tt.y + tt.w) * 0.5f - pr.y, 0.1f * pr.w);
    float g2 = __logf(__fdividef(tt.z - tt.x, pr.z)) * 5.0f;
    float g3 = __logf(__fdividef(tt.w - tt.y, pr.w)) * 5.0f;
    float d0 = ld.x - g0, d1 = ld.y - g1, d2 = ld.z - g2, d3 = ld.w - g3;
    float a0 = fabsf(d0), a1 = fabsf(d1), a2 = fabsf(d2), a3 = fabsf(d3);
    return (a0 < 1.f ? 0.5f * d0 * d0 : a0 - 0.5f)
         + (a1 < 1.f ? 0.5f * d1 * d1 : a1 - 0.5f)
         + (a2 < 1.f ? 0.5f * d2 * d2 : a2 - 0.5f)
         + (a3 < 1.f ? 0.5f * d3 * d3 : a3 - 0.5f);
}

__device__ __forceinline__ float lse2(float c0, float c1)
{
#pragma clang fp contract(off)
    float mm = fmaxf(c0, c1), mn = fminf(c0, c1);
    return mm + __logf(1.f + __expf(mn - mm));
}

// ---------------- K1: IoU + per-prior best + PRE-FIX losses + mine, all fused ----------
// grid (32 tiles, 32 batches) x 256 threads; each thread owns 4 CONSECUTIVE priors.
__global__ __launch_bounds__(256) void kern1(
        const float* __restrict__ loc, const float* __restrict__ conf,
        const float* __restrict__ priors, const float* __restrict__ targets,
        float* __restrict__ mine, u64* __restrict__ bpk_part,
        float* __restrict__ part_sl1, float* __restrict__ part_cep, int* __restrict__ part_np,
        float* __restrict__ sl_tot, float* __restrict__ c_tot,
        int* __restrict__ np_tot, int* __restrict__ done_cnt)
{
#pragma clang fp contract(off)
    __shared__ __align__(16) float4 tbc[NO];   // truth corners
    __shared__ float ta[NO], tlab[NO];
    __shared__ u64 keys[NO];
    __shared__ float rs0[4], rs1[4];
    __shared__ int rc[4];
    const int b = blockIdx.y, x = blockIdx.x, tid = threadIdx.x;
    if (b == 0 && x == 0 && tid == 0) {        // init accumulators for kern3 (runs after us)
        *sl_tot = 0.f; *c_tot = 0.f; *np_tot = 0; *done_cnt = 0;
    }
    if (tid < NO * 5) {
        int o = tid / 5, c = tid % 5;
        float v = targets[b * NO * 5 + tid];
        if (c < 4) ((float*)&tbc[o])[c] = v; else tlab[o] = v;
    }
    if (tid < NO) keys[tid] = 0ull;
    __syncthreads();
    if (tid < NO) {
        float4 t = tbc[tid];
        ta[tid] = (t.z - t.x) * (t.w - t.y);
    }
    __syncthreads();

    const int p0 = x * 1024 + tid * 4;
    float4 pr[4];
    float px1[4], py1[4], px2[4], py2[4], ab[4];
#pragma unroll
    for (int j = 0; j < 4; ++j) {
        pr[j] = ((const float4*)priors)[p0 + j];
        px1[j] = pr[j].x - pr[j].z * 0.5f;
        py1[j] = pr[j].y - pr[j].w * 0.5f;
        px2[j] = pr[j].x + pr[j].z * 0.5f;
        py2[j] = pr[j].y + pr[j].w * 0.5f;
        ab[j]  = pr[j].z * pr[j].w;
    }
    // per-prior best truth as packed u64: (iou_bits << 6) | (63 - o)
    // max => largest iou, tie => smallest o (reference first-max argmax)
    u64 bk[4] = {0ull, 0ull, 0ull, 0ull};
    for (int o = 0; o < NO; ++o) {             // wave-uniform o: broadcast LDS reads
        float4 tt = tbc[o];
        float aa = ta[o];
        float iou4[4];
#pragma unroll
        for (int j = 0; j < 4; ++j) {
            float iou = iou_corners(px1[j], py1[j], px2[j], py2[j], ab[j],
                                    tt.x, tt.y, tt.z, tt.w, aa);
            iou4[j] = iou;
            u64 ko = ((u64)__float_as_uint(iou) << 6) | (u64)(63 - o);
            bk[j] = bk[j] > ko ? bk[j] : ko;
        }
        // per-truth best prior: cheap value-only filter, rare full path
        float vm = fmaxf(fmaxf(iou4[0], iou4[1]), fmaxf(iou4[2], iou4[3]));
        u64 cur = keys[o];
        if (__float_as_uint(vm) > (u32)(cur >> 32)) {
            float bi = iou4[3]; int bp = p0 + 3;
            if (iou4[2] >= bi) { bi = iou4[2]; bp = p0 + 2; }
            if (iou4[1] >= bi) { bi = iou4[1]; bp = p0 + 1; }
            if (iou4[0] >= bi) { bi = iou4[0]; bp = p0 + 0; }
            atomicMax(&keys[o], ((u64)__float_as_uint(bi) << 32) | (u64)(~(u32)bp));
        }
    }

    // ---- pre-fix losses straight from registers ----
    const size_t gbase = (size_t)b * NP + p0;
    float4 cfa = ((const float4*)conf)[gbase / 2];
    float4 cfb = ((const float4*)conf)[gbase / 2 + 1];
    float c0[4] = {cfa.x, cfa.z, cfb.x, cfb.z};
    float c1[4] = {cfa.y, cfa.w, cfb.y, cfb.w};
    float4 mout;
    float s_sl1 = 0.f, s_cep = 0.f;
    int np = 0;
#pragma unroll
    for (int j = 0; j < 4; ++j) {
        u32 vb = (u32)(bk[j] >> 6);
        float bv = __uint_as_float(vb);
        int o = 63 - (int)(bk[j] & 63);
        int cf = (bv < THRESH) ? 0 : ((int)tlab[o] + 1);
        bool pos = cf > 0;
        float4 ld = ((const float4*)loc)[gbase + j];
        float sl1 = smooth_l1_sum(ld, pr[j], tbc[o]);
        float ce = lse2(c0[j], c1[j]) - ((cf == 0) ? c0[j] : c1[j]);
        if (pos) { s_sl1 += sl1; s_cep += ce; np++; }
        ((float*)&mout)[j] = pos ? 0.f : ce;
    }
    ((float4*)mine)[gbase / 4] = mout;

#pragma unroll
    for (int m = 32; m; m >>= 1) {
        s_sl1 += __shfl_xor(s_sl1, m, 64);
        s_cep += __shfl_xor(s_cep, m, 64);
        np    += __shfl_xor(np, m, 64);
    }
    int lane = tid & 63, w = tid >> 6;
    if (lane == 0) { rs0[w] = s_sl1; rs1[w] = s_cep; rc[w] = np; }
    __syncthreads();
    if (tid == 0) {
        float t0 = 0.f, t1 = 0.f; int t2 = 0;
        for (int i = 0; i < 4; ++i) { t0 += rs0[i]; t1 += rs1[i]; t2 += rc[i]; }
        part_sl1[b * 32 + x] = t0;
        part_cep[b * 32 + x] = t1;
        part_np [b * 32 + x] = t2;
    }
    if (tid < NO) bpk_part[(b * 32 + x) * 32 + tid] = keys[tid];  // after the sync above
}

// ---------------- K3: fix + deltas + per-wave-hist radix-select top-k + finalize --------
// one block per batch, 1024 threads (16 waves)
__global__ __launch_bounds__(1024) void kern3(
        const float* __restrict__ loc, const float* __restrict__ conf,
        const float* __restrict__ priors, const float* __restrict__ targets,
        const u64* __restrict__ bpk_part, const float* __restrict__ mine,
        const float* __restrict__ part_sl1, const float* __restrict__ part_cep,
        const int* __restrict__ part_np,
        float* __restrict__ sl_tot, float* __restrict__ c_tot,
        int* __restrict__ np_tot, int* __restrict__ done_cnt,
        float* __restrict__ out)
{
#pragma clang fp contract(off)
    const int b = blockIdx.x, tid = threadIdx.x;
    const int wave = tid >> 6, lane = tid & 63;
    __shared__ __align__(16) float4 tbc[NO];
    __shared__ float tlab[NO], tas[NO];
    __shared__ u32 pp[NO];
    __shared__ u32 flags[1024];                 // 32768-bit mask of forced priors
    __shared__ __align__(16) int hist[16][256]; // per-wave private histograms (16 KB)
    __shared__ __align__(16) int total[256];
    __shared__ u32 sh_prefix;
    __shared__ int sh_kk;
    __shared__ float sh_sl1, sh_cep;
    __shared__ int sh_np;
    __shared__ float rs[16];

    if (tid < NO * 5) {
        int o = tid / 5, c = tid % 5;
        float v = targets[b * NO * 5 + tid];
        if (c < 4) ((float*)&tbc[o])[c] = v; else tlab[o] = v;
    }
    flags[tid] = 0u;

    const float* mb = mine + (size_t)b * NP;
    float v[32];
#pragma unroll
    for (int q = 0; q < 8; ++q) {
        float4 t4 = ((const float4*)mb)[q * 1024 + tid];
        v[4 * q] = t4.x; v[4 * q + 1] = t4.y; v[4 * q + 2] = t4.z; v[4 * q + 3] = t4.w;
    }
    __syncthreads();
    if (tid < NO) {
        float4 t = tbc[tid];
        tas[tid] = (t.z - t.x) * (t.w - t.y);
        // resolve per-truth best prior across the 32 x-tiles
        u64 key = 0ull;
        for (int xx = 0; xx < 32; ++xx) {
            u64 t2 = bpk_part[(b * 32 + xx) * 32 + tid];
            key = t2 > key ? t2 : key;
        }
        pp[tid] = (key >> 32) ? ~(u32)key : 0u;   // all-zero row => argmax = 0
    }
    __syncthreads();
    if (tid < NO) {
        const int o = tid;
        const u32 p = pp[o];
        float dsl1 = 0.f, dcep = 0.f; int dnp = 0;
        bool last = true;
        for (int o2 = o + 1; o2 < NO; ++o2)
            if (pp[o2] == p) { last = false; break; }   // later o overwrites same prior
        if (last) {
            float4 prr = ((const float4*)priors)[p];
            float px1 = prr.x - prr.z * 0.5f, py1 = prr.y - prr.w * 0.5f;
            float px2 = prr.x + prr.z * 0.5f, py2 = prr.y + prr.w * 0.5f;
            float ab = prr.z * prr.w;
            // pre-fix best truth for p (natural order, strict > == first-max)
            float bv = -1.f; int bo_ = 0;
            for (int o2 = 0; o2 < NO; ++o2) {
                float4 t2 = tbc[o2];
                float i2 = iou_corners(px1, py1, px2, py2, ab, t2.x, t2.y, t2.z, t2.w, tas[o2]);
                if (i2 > bv) { bv = i2; bo_ = o2; }
            }
            int cf_pre = (bv < THRESH) ? 0 : ((int)tlab[bo_] + 1);
            size_t gp = (size_t)b * NP + p;
            float4 ld = ((const float4*)loc)[gp];
            float2 c = ((const float2*)conf)[gp];
            float lse = lse2(c.x, c.y);
            int cf_new = (int)tlab[o] + 1;               // forced positive
            dsl1 = smooth_l1_sum(ld, prr, tbc[o]);
            dcep = lse - ((cf_new == 0) ? c.x : c.y);
            dnp = 1;
            if (cf_pre > 0) {                            // remove pre-fix contribution
                dsl1 -= smooth_l1_sum(ld, prr, tbc[bo_]);
                dcep -= lse - ((cf_pre == 0) ? c.x : c.y);
                dnp = 0;
            }
            atomicOr(&flags[p >> 5], 1u << (p & 31));
        }
        // batch stats: 32 kern1 partials + this lane's delta, wave-0 reduce
        float a = part_sl1[b * 32 + o] + dsl1;
        float d = part_cep[b * 32 + o] + dcep;
        int   n = part_np [b * 32 + o] + dnp;
#pragma unroll
        for (int m = 16; m; m >>= 1) {
            a += __shfl_xor(a, m, 32);
            d += __shfl_xor(d, m, 32);
            n += __shfl_xor(n, m, 32);
        }
        if (o == 0) {
            sh_sl1 = a; sh_cep = d; sh_np = n;
            sh_prefix = 0u; sh_kk = min(7 * n, NP - 1);
        }
    }
    __syncthreads();
    // zero forced priors in-register (they become pos => mine 0)
#pragma unroll
    for (int q = 0; q < 8; ++q) {
        u32 word = flags[q * 128 + (tid >> 3)];
#pragma unroll
        for (int c = 0; c < 4; ++c)
            if ((word >> (((tid & 7) << 2) + c)) & 1u) v[4 * q + c] = 0.f;
    }
    const int k = sh_kk;
    float topk = 0.f;
    if (k > 0) {
        int* myh = &hist[wave][0];
        for (int pass = 0; pass < 4; ++pass) {
            // clear per-wave histograms
#pragma unroll
            for (int i = 0; i < 4; ++i) ((int*)hist)[tid + i * 1024] = 0;
            __syncthreads();
            const int shift = 24 - 8 * pass;
            const u32 pfx = sh_prefix;
#pragma unroll 8
            for (int j = 0; j < 32; ++j) {
                u32 kb = __float_as_uint(v[j]);
                if ((u32)(((u64)kb) >> (shift + 8)) == pfx)   // 64-bit shift: defined at 32
                    atomicAdd(&myh[(kb >> shift) & 255], 1);
            }
            __syncthreads();
            if (tid < 256) {                 // reduce 16 wave-copies; 2 lanes/bank = free
                int s = 0;
#pragma unroll
                for (int w2 = 0; w2 < 16; ++w2) s += hist[w2][tid];
                total[tid] = s;
            }
            __syncthreads();
            if (tid < 64) {                  // suffix-scan select over 256 bins
                int4 h4 = ((const int4*)total)[tid];
                int s3 = h4.w, s2 = h4.z + s3, s1 = h4.y + s2, s0 = h4.x + s1;
                int acc = s0;
#pragma unroll
                for (int off = 1; off < 64; off <<= 1) {
                    int u = __shfl_down(acc, off, 64);
                    if (tid + off < 64) acc += u;
                }
                int excl = acc - s0;
                int kk = sh_kk;
                int cand = -1, nkk = 0;
                if (excl + s3 >= kk)      { cand = 4 * tid + 3; nkk = kk - excl; }
                else if (excl + s2 >= kk) { cand = 4 * tid + 2; nkk = kk - excl - s3; }
                else if (excl + s1 >= kk) { cand = 4 * tid + 1; nkk = kk - excl - s2; }
                else if (excl + s0 >= kk) { cand = 4 * tid + 0; nkk = kk - excl - s1; }
                int cmax = cand;
#pragma unroll
                for (int off = 1; off < 64; off <<= 1) cmax = max(cmax, __shfl_xor(cmax, off, 64));
                if (cand >= 0 && cand == cmax) {
                    sh_prefix = (pfx << 8) | (u32)(cand & 255);
                    sh_kk = nkk;
                }
            }
            __syncthreads();
        }
        const u32 T = sh_prefix;               // exact k-th largest key
        const float tval = __uint_as_float(T);
        float s = 0.f;
#pragma unroll
        for (int j = 0; j < 32; ++j)
            if (__float_as_uint(v[j]) > T) s += v[j];
#pragma unroll
        for (int m = 32; m; m >>= 1) s += __shfl_xor(s, m, 64);
        if (lane == 0) rs[wave] = s;
        __syncthreads();
        if (tid == 0) {
            float st = 0.f;
            for (int i = 0; i < 16; ++i) st += rs[i];
            topk = st + (float)sh_kk * tval;   // sh_kk = #ties at T still selected
        }
    }
    if (tid == 0) {                            // accumulate + last-block finalize
        atomicAdd(sl_tot, sh_sl1);
        atomicAdd(c_tot, sh_cep + topk);
        atomicAdd(np_tot, sh_np);
        __threadfence();
        int d = atomicAdd(done_cnt, 1);
        if (d == NB - 1) {
            float sl = atomicAdd(sl_tot, 0.f);   // coherent reads incl. all contributions
            float cc = atomicAdd(c_tot, 0.f);
            int   np = atomicAdd(np_tot, 0);
            float N = fmaxf((float)np, 1.f);
            out[0] = sl / N;
            out[1] = cc / N;
        }
    }
}

extern "C" void kernel_launch(void* const* d_in, const int* in_sizes, int n_in,
                              void* d_out, int out_size, void* d_ws, size_t ws_size,
                              hipStream_t stream) {
    const float* loc     = (const float*)d_in[0];   // (B,P,4)
    const float* conf    = (const float*)d_in[1];   // (B,P,2)
    const float* priors  = (const float*)d_in[2];   // (P,4)
    const float* targets = (const float*)d_in[3];   // (B,O,5)
    float* out = (float*)d_out;

    char* ws = (char*)d_ws;
    float* mine     = (float*)ws;                       // 4 MB, fully written by K1
    u64*   bpk_part = (u64*)(ws + 4194304);             // 256 KB [b][x][o], fully written by K1
    float* part_sl1 = (float*)(ws + 4456448);           // [b][32] kern1 partials
    float* part_cep = (float*)(ws + 4460544);
    int*   part_np  = (int*)(ws + 4464640);
    float* sl_tot   = (float*)(ws + 4468736);           // zero-inited by kern1 block (0,0)
    float* c_tot    = (float*)(ws + 4468740);
    int*   np_tot   = (int*)(ws + 4468744);
    int*   done_cnt = (int*)(ws + 4468748);

    dim3 g1(32, NB);
    kern1<<<g1, 256, 0, stream>>>(loc, conf, priors, targets, mine, bpk_part,
                                  part_sl1, part_cep, part_np,
                                  sl_tot, c_tot, np_tot, done_cnt);
    kern3<<<NB, 1024, 0, stream>>>(loc, conf, priors, targets, bpk_part, mine,
                                   part_sl1, part_cep, part_np,
                                   sl_tot, c_tot, np_tot, done_cnt, out);
}

// Round 6
// 149.802 us; speedup vs baseline: 1.3481x; 1.3481x over previous
//
#include <hip/hip_runtime.h>
#include <stdint.h>

#define NB 32
#define NP 32768
#define NO 32
#define THRESH 0.35f

typedef unsigned long long u64;
typedef unsigned int u32;

// fast IoU from prior corners + truth corners. kern1's additions and kern3's
// delta-subtractions must cancel bit-exactly, so BOTH use this helper.
__device__ __forceinline__ float iou_corners(float px1, float py1, float px2, float py2, float ab,
                                             float tx1, float ty1, float tx2, float ty2, float aa)
{
#pragma clang fp contract(off)
    float iw = fminf(tx2, px2) - fmaxf(tx1, px1);
    float ih = fminf(ty2, py2) - fmaxf(ty1, py1);
    iw = fmaxf(iw, 0.f); ih = fmaxf(ih, 0.f);
    float inter = iw * ih;
    return __fdividef(inter, aa + ab - inter);
}

// smooth-L1 of (loc - encode(truth, prior)), summed over 4 coords
__device__ __forceinline__ float smooth_l1_sum(float4 ld, float4 pr, float4 tt)
{
#pragma clang fp contract(off)
    float g0 = __fdividef((tt.x + tt.z) * 0.5f - pr.x, 0.1f * pr.z);
    float g1 = __fdividef((tt.y + tt.w) * 0.5f - pr.y, 0.1f * pr.w);
    float g2 = __logf(__fdividef(tt.z - tt.x, pr.z)) * 5.0f;
    float g3 = __logf(__fdividef(tt.w - tt.y, pr.w)) * 5.0f;
    float d0 = ld.x - g0, d1 = ld.y - g1, d2 = ld.z - g2, d3 = ld.w - g3;
    float a0 = fabsf(d0), a1 = fabsf(d1), a2 = fabsf(d2), a3 = fabsf(d3);
    return (a0 < 1.f ? 0.5f * d0 * d0 : a0 - 0.5f)
         + (a1 < 1.f ? 0.5f * d1 * d1 : a1 - 0.5f)
         + (a2 < 1.f ? 0.5f * d2 * d2 : a2 - 0.5f)
         + (a3 < 1.f ? 0.5f * d3 * d3 : a3 - 0.5f);
}

__device__ __forceinline__ float lse2(float c0, float c1)
{
#pragma clang fp contract(off)
    float mm = fmaxf(c0, c1), mn = fminf(c0, c1);
    return mm + __logf(1.f + __expf(mn - mm));
}

// ---------------- K1: IoU + per-prior best + PRE-FIX losses + mine, all fused ----------
// grid (32 tiles, 32 batches) x 256 threads; each thread owns 4 CONSECUTIVE priors.
// NOTE: o is STAGGERED per lane (o = (it + lane%32) & 31). This is load-bearing:
// it spreads keys[o] atomics over 32 LDS addresses (2 lanes/addr = conflict-free).
// A wave-uniform o funnels 64-lane same-address DS atomics -> DS-pipe serialization
// (measured R5: kern1 44->95 us with VALUBusy unchanged).
__global__ __launch_bounds__(256) void kern1(
        const float* __restrict__ loc, const float* __restrict__ conf,
        const float* __restrict__ priors, const float* __restrict__ targets,
        float* __restrict__ mine, u64* __restrict__ bpk_part,
        float* __restrict__ part_sl1, float* __restrict__ part_cep, int* __restrict__ part_np,
        float* __restrict__ sl_tot, float* __restrict__ c_tot,
        int* __restrict__ np_tot, int* __restrict__ done_cnt)
{
#pragma clang fp contract(off)
    __shared__ __align__(16) float4 tbc[NO];   // truth corners
    __shared__ float ta[NO], tlab[NO];
    __shared__ u64 keys[NO];
    __shared__ float rs0[4], rs1[4];
    __shared__ int rc[4];
    const int b = blockIdx.y, x = blockIdx.x, tid = threadIdx.x;
    if (b == 0 && x == 0 && tid == 0) {        // init accumulators for kern3 (runs after us)
        *sl_tot = 0.f; *c_tot = 0.f; *np_tot = 0; *done_cnt = 0;
    }
    if (tid < NO * 5) {
        int o = tid / 5, c = tid % 5;
        float v = targets[b * NO * 5 + tid];
        if (c < 4) ((float*)&tbc[o])[c] = v; else tlab[o] = v;
    }
    if (tid < NO) keys[tid] = 0ull;
    __syncthreads();
    if (tid < NO) {
        float4 t = tbc[tid];
        ta[tid] = (t.z - t.x) * (t.w - t.y);
    }
    __syncthreads();

    const int p0 = x * 1024 + tid * 4;
    float4 pr[4];
    float px1[4], py1[4], px2[4], py2[4], ab[4];
#pragma unroll
    for (int j = 0; j < 4; ++j) {
        pr[j] = ((const float4*)priors)[p0 + j];
        px1[j] = pr[j].x - pr[j].z * 0.5f;
        py1[j] = pr[j].y - pr[j].w * 0.5f;
        px2[j] = pr[j].x + pr[j].z * 0.5f;
        py2[j] = pr[j].y + pr[j].w * 0.5f;
        ab[j]  = pr[j].z * pr[j].w;
    }
    // per-prior best truth as packed u64: (iou_bits << 6) | (63 - o)
    // max => largest iou, tie => smallest o (reference first-max argmax)
    u64 bk[4] = {0ull, 0ull, 0ull, 0ull};
    const int lane_o = tid & 31;   // stagger (see note above)
    for (int it = 0; it < NO; ++it) {
        const int o = (it + lane_o) & 31;
        float4 tt = tbc[o];
        float aa = ta[o];
        float iou4[4];
#pragma unroll
        for (int j = 0; j < 4; ++j) {
            float iou = iou_corners(px1[j], py1[j], px2[j], py2[j], ab[j],
                                    tt.x, tt.y, tt.z, tt.w, aa);
            iou4[j] = iou;
            u64 ko = ((u64)__float_as_uint(iou) << 6) | (u64)(63 - o);
            bk[j] = bk[j] > ko ? bk[j] : ko;
        }
        // per-truth best prior: cheap value-only filter, rare full path
        float vm = fmaxf(fmaxf(iou4[0], iou4[1]), fmaxf(iou4[2], iou4[3]));
        u64 cur = keys[o];
        if (__float_as_uint(vm) > (u32)(cur >> 32)) {
            float bi = iou4[3]; int bp = p0 + 3;
            if (iou4[2] >= bi) { bi = iou4[2]; bp = p0 + 2; }
            if (iou4[1] >= bi) { bi = iou4[1]; bp = p0 + 1; }
            if (iou4[0] >= bi) { bi = iou4[0]; bp = p0 + 0; }
            atomicMax(&keys[o], ((u64)__float_as_uint(bi) << 32) | (u64)(~(u32)bp));
        }
    }

    // ---- pre-fix losses straight from registers ----
    const size_t gbase = (size_t)b * NP + p0;
    float4 cfa = ((const float4*)conf)[gbase / 2];
    float4 cfb = ((const float4*)conf)[gbase / 2 + 1];
    float c0[4] = {cfa.x, cfa.z, cfb.x, cfb.z};
    float c1[4] = {cfa.y, cfa.w, cfb.y, cfb.w};
    float4 mout;
    float s_sl1 = 0.f, s_cep = 0.f;
    int np = 0;
#pragma unroll
    for (int j = 0; j < 4; ++j) {
        u32 vb = (u32)(bk[j] >> 6);
        float bv = __uint_as_float(vb);
        int o = 63 - (int)(bk[j] & 63);
        int cf = (bv < THRESH) ? 0 : ((int)tlab[o] + 1);
        bool pos = cf > 0;
        float4 ld = ((const float4*)loc)[gbase + j];
        float sl1 = smooth_l1_sum(ld, pr[j], tbc[o]);
        float ce = lse2(c0[j], c1[j]) - ((cf == 0) ? c0[j] : c1[j]);
        if (pos) { s_sl1 += sl1; s_cep += ce; np++; }
        ((float*)&mout)[j] = pos ? 0.f : ce;
    }
    ((float4*)mine)[gbase / 4] = mout;

#pragma unroll
    for (int m = 32; m; m >>= 1) {
        s_sl1 += __shfl_xor(s_sl1, m, 64);
        s_cep += __shfl_xor(s_cep, m, 64);
        np    += __shfl_xor(np, m, 64);
    }
    int lane = tid & 63, w = tid >> 6;
    if (lane == 0) { rs0[w] = s_sl1; rs1[w] = s_cep; rc[w] = np; }
    __syncthreads();
    if (tid == 0) {
        float t0 = 0.f, t1 = 0.f; int t2 = 0;
        for (int i = 0; i < 4; ++i) { t0 += rs0[i]; t1 += rs1[i]; t2 += rc[i]; }
        part_sl1[b * 32 + x] = t0;
        part_cep[b * 32 + x] = t1;
        part_np [b * 32 + x] = t2;
    }
    if (tid < NO) bpk_part[(b * 32 + x) * 32 + tid] = keys[tid];  // after the sync above
}

// ---------------- K3: fix + deltas + per-wave-hist radix-select top-k + finalize --------
// one block per batch, 1024 threads (16 waves)
__global__ __launch_bounds__(1024) void kern3(
        const float* __restrict__ loc, const float* __restrict__ conf,
        const float* __restrict__ priors, const float* __restrict__ targets,
        const u64* __restrict__ bpk_part, const float* __restrict__ mine,
        const float* __restrict__ part_sl1, const float* __restrict__ part_cep,
        const int* __restrict__ part_np,
        float* __restrict__ sl_tot, float* __restrict__ c_tot,
        int* __restrict__ np_tot, int* __restrict__ done_cnt,
        float* __restrict__ out)
{
#pragma clang fp contract(off)
    const int b = blockIdx.x, tid = threadIdx.x;
    const int wave = tid >> 6, lane = tid & 63;
    __shared__ __align__(16) float4 tbc[NO];
    __shared__ float tlab[NO], tas[NO];
    __shared__ u32 pp[NO];
    __shared__ u32 flags[1024];                 // 32768-bit mask of forced priors
    __shared__ __align__(16) int hist[16][256]; // per-wave private histograms (16 KB)
    __shared__ __align__(16) int total[256];
    __shared__ u32 sh_prefix;
    __shared__ int sh_kk;
    __shared__ float sh_sl1, sh_cep;
    __shared__ int sh_np;
    __shared__ float rs[16];

    if (tid < NO * 5) {
        int o = tid / 5, c = tid % 5;
        float v = targets[b * NO * 5 + tid];
        if (c < 4) ((float*)&tbc[o])[c] = v; else tlab[o] = v;
    }
    flags[tid] = 0u;

    const float* mb = mine + (size_t)b * NP;
    float v[32];
#pragma unroll
    for (int q = 0; q < 8; ++q) {
        float4 t4 = ((const float4*)mb)[q * 1024 + tid];
        v[4 * q] = t4.x; v[4 * q + 1] = t4.y; v[4 * q + 2] = t4.z; v[4 * q + 3] = t4.w;
    }
    __syncthreads();
    if (tid < NO) {
        float4 t = tbc[tid];
        tas[tid] = (t.z - t.x) * (t.w - t.y);
        // resolve per-truth best prior across the 32 x-tiles
        u64 key = 0ull;
        for (int xx = 0; xx < 32; ++xx) {
            u64 t2 = bpk_part[(b * 32 + xx) * 32 + tid];
            key = t2 > key ? t2 : key;
        }
        pp[tid] = (key >> 32) ? ~(u32)key : 0u;   // all-zero row => argmax = 0
    }
    __syncthreads();
    if (tid < NO) {
        const int o = tid;
        const u32 p = pp[o];
        float dsl1 = 0.f, dcep = 0.f; int dnp = 0;
        bool last = true;
        for (int o2 = o + 1; o2 < NO; ++o2)
            if (pp[o2] == p) { last = false; break; }   // later o overwrites same prior
        if (last) {
            float4 prr = ((const float4*)priors)[p];
            float px1 = prr.x - prr.z * 0.5f, py1 = prr.y - prr.w * 0.5f;
            float px2 = prr.x + prr.z * 0.5f, py2 = prr.y + prr.w * 0.5f;
            float ab = prr.z * prr.w;
            // pre-fix best truth for p (natural order, strict > == first-max)
            float bv = -1.f; int bo_ = 0;
            for (int o2 = 0; o2 < NO; ++o2) {
                float4 t2 = tbc[o2];
                float i2 = iou_corners(px1, py1, px2, py2, ab, t2.x, t2.y, t2.z, t2.w, tas[o2]);
                if (i2 > bv) { bv = i2; bo_ = o2; }
            }
            int cf_pre = (bv < THRESH) ? 0 : ((int)tlab[bo_] + 1);
            size_t gp = (size_t)b * NP + p;
            float4 ld = ((const float4*)loc)[gp];
            float2 c = ((const float2*)conf)[gp];
            float lse = lse2(c.x, c.y);
            int cf_new = (int)tlab[o] + 1;               // forced positive
            dsl1 = smooth_l1_sum(ld, prr, tbc[o]);
            dcep = lse - ((cf_new == 0) ? c.x : c.y);
            dnp = 1;
            if (cf_pre > 0) {                            // remove pre-fix contribution
                dsl1 -= smooth_l1_sum(ld, prr, tbc[bo_]);
                dcep -= lse - ((cf_pre == 0) ? c.x : c.y);
                dnp = 0;
            }
            atomicOr(&flags[p >> 5], 1u << (p & 31));
        }
        // batch stats: 32 kern1 partials + this lane's delta, wave-0 reduce
        float a = part_sl1[b * 32 + o] + dsl1;
        float d = part_cep[b * 32 + o] + dcep;
        int   n = part_np [b * 32 + o] + dnp;
#pragma unroll
        for (int m = 16; m; m >>= 1) {
            a += __shfl_xor(a, m, 32);
            d += __shfl_xor(d, m, 32);
            n += __shfl_xor(n, m, 32);
        }
        if (o == 0) {
            sh_sl1 = a; sh_cep = d; sh_np = n;
            sh_prefix = 0u; sh_kk = min(7 * n, NP - 1);
        }
    }
    __syncthreads();
    // zero forced priors in-register (they become pos => mine 0)
#pragma unroll
    for (int q = 0; q < 8; ++q) {
        u32 word = flags[q * 128 + (tid >> 3)];
#pragma unroll
        for (int c = 0; c < 4; ++c)
            if ((word >> (((tid & 7) << 2) + c)) & 1u) v[4 * q + c] = 0.f;
    }
    const int k = sh_kk;
    float topk = 0.f;
    if (k > 0) {
        int* myh = &hist[wave][0];
        for (int pass = 0; pass < 4; ++pass) {
            // clear per-wave histograms
#pragma unroll
            for (int i = 0; i < 4; ++i) ((int*)hist)[tid + i * 1024] = 0;
            __syncthreads();
            const int shift = 24 - 8 * pass;
            const u32 pfx = sh_prefix;
#pragma unroll 8
            for (int j = 0; j < 32; ++j) {
                u32 kb = __float_as_uint(v[j]);
                if ((u32)(((u64)kb) >> (shift + 8)) == pfx)   // 64-bit shift: defined at 32
                    atomicAdd(&myh[(kb >> shift) & 255], 1);
            }
            __syncthreads();
            if (tid < 256) {                 // reduce 16 wave-copies; 2 lanes/bank = free
                int s = 0;
#pragma unroll
                for (int w2 = 0; w2 < 16; ++w2) s += hist[w2][tid];
                total[tid] = s;
            }
            __syncthreads();
            if (tid < 64) {                  // suffix-scan select over 256 bins
                int4 h4 = ((const int4*)total)[tid];
                int s3 = h4.w, s2 = h4.z + s3, s1 = h4.y + s2, s0 = h4.x + s1;
                int acc = s0;
#pragma unroll
                for (int off = 1; off < 64; off <<= 1) {
                    int u = __shfl_down(acc, off, 64);
                    if (tid + off < 64) acc += u;
                }
                int excl = acc - s0;
                int kk = sh_kk;
                int cand = -1, nkk = 0;
                if (excl + s3 >= kk)      { cand = 4 * tid + 3; nkk = kk - excl; }
                else if (excl + s2 >= kk) { cand = 4 * tid + 2; nkk = kk - excl - s3; }
                else if (excl + s1 >= kk) { cand = 4 * tid + 1; nkk = kk - excl - s2; }
                else if (excl + s0 >= kk) { cand = 4 * tid + 0; nkk = kk - excl - s1; }
                int cmax = cand;
#pragma unroll
                for (int off = 1; off < 64; off <<= 1) cmax = max(cmax, __shfl_xor(cmax, off, 64));
                if (cand >= 0 && cand == cmax) {
                    sh_prefix = (pfx << 8) | (u32)(cand & 255);
                    sh_kk = nkk;
                }
            }
            __syncthreads();
        }
        const u32 T = sh_prefix;               // exact k-th largest key
        const float tval = __uint_as_float(T);
        float s = 0.f;
#pragma unroll
        for (int j = 0; j < 32; ++j)
            if (__float_as_uint(v[j]) > T) s += v[j];
#pragma unroll
        for (int m = 32; m; m >>= 1) s += __shfl_xor(s, m, 64);
        if (lane == 0) rs[wave] = s;
        __syncthreads();
        if (tid == 0) {
            float st = 0.f;
            for (int i = 0; i < 16; ++i) st += rs[i];
            topk = st + (float)sh_kk * tval;   // sh_kk = #ties at T still selected
        }
    }
    if (tid == 0) {                            // accumulate + last-block finalize
        atomicAdd(sl_tot, sh_sl1);
        atomicAdd(c_tot, sh_cep + topk);
        atomicAdd(np_tot, sh_np);
        __threadfence();
        int d = atomicAdd(done_cnt, 1);
        if (d == NB - 1) {
            float sl = atomicAdd(sl_tot, 0.f);   // coherent reads incl. all contributions
            float cc = atomicAdd(c_tot, 0.f);
            int   np = atomicAdd(np_tot, 0);
            float N = fmaxf((float)np, 1.f);
            out[0] = sl / N;
            out[1] = cc / N;
        }
    }
}

extern "C" void kernel_launch(void* const* d_in, const int* in_sizes, int n_in,
                              void* d_out, int out_size, void* d_ws, size_t ws_size,
                              hipStream_t stream) {
    const float* loc     = (const float*)d_in[0];   // (B,P,4)
    const float* conf    = (const float*)d_in[1];   // (B,P,2)
    const float* priors  = (const float*)d_in[2];   // (P,4)
    const float* targets = (const float*)d_in[3];   // (B,O,5)
    float* out = (float*)d_out;

    char* ws = (char*)d_ws;
    float* mine     = (float*)ws;                       // 4 MB, fully written by K1
    u64*   bpk_part = (u64*)(ws + 4194304);             // 256 KB [b][x][o], fully written by K1
    float* part_sl1 = (float*)(ws + 4456448);           // [b][32] kern1 partials
    float* part_cep = (float*)(ws + 4460544);
    int*   part_np  = (int*)(ws + 4464640);
    float* sl_tot   = (float*)(ws + 4468736);           // zero-inited by kern1 block (0,0)
    float* c_tot    = (float*)(ws + 4468740);
    int*   np_tot   = (int*)(ws + 4468744);
    int*   done_cnt = (int*)(ws + 4468748);

    dim3 g1(32, NB);
    kern1<<<g1, 256, 0, stream>>>(loc, conf, priors, targets, mine, bpk_part,
                                  part_sl1, part_cep, part_np,
                                  sl_tot, c_tot, np_tot, done_cnt);
    kern3<<<NB, 1024, 0, stream>>>(loc, conf, priors, targets, bpk_part, mine,
                                   part_sl1, part_cep, part_np,
                                   sl_tot, c_tot, np_tot, done_cnt, out);
}

// Round 7
// 149.704 us; speedup vs baseline: 1.3490x; 1.0007x over previous
//
#include <hip/hip_runtime.h>
#include <stdint.h>

#define NB 32
#define NP 32768
#define NO 32
#define THRESH 0.35f

typedef unsigned long long u64;
typedef unsigned int u32;

// fast IoU from prior corners + truth corners. kern1's additions and kern3's
// delta-subtractions must cancel bit-exactly, so BOTH use this helper.
__device__ __forceinline__ float iou_corners(float px1, float py1, float px2, float py2, float ab,
                                             float tx1, float ty1, float tx2, float ty2, float aa)
{
#pragma clang fp contract(off)
    float iw = fminf(tx2, px2) - fmaxf(tx1, px1);
    float ih = fminf(ty2, py2) - fmaxf(ty1, py1);
    iw = fmaxf(iw, 0.f); ih = fmaxf(ih, 0.f);
    float inter = iw * ih;
    return __fdividef(inter, aa + ab - inter);
}

// smooth-L1 of (loc - encode(truth, prior)), summed over 4 coords
__device__ __forceinline__ float smooth_l1_sum(float4 ld, float4 pr, float4 tt)
{
#pragma clang fp contract(off)
    float g0 = __fdividef((tt.x + tt.z) * 0.5f - pr.x, 0.1f * pr.z);
    float g1 = __fdividef((tt.y + tt.w) * 0.5f - pr.y, 0.1f * pr.w);
    float g2 = __logf(__fdividef(tt.z - tt.x, pr.z)) * 5.0f;
    float g3 = __logf(__fdividef(tt.w - tt.y, pr.w)) * 5.0f;
    float d0 = ld.x - g0, d1 = ld.y - g1, d2 = ld.z - g2, d3 = ld.w - g3;
    float a0 = fabsf(d0), a1 = fabsf(d1), a2 = fabsf(d2), a3 = fabsf(d3);
    return (a0 < 1.f ? 0.5f * d0 * d0 : a0 - 0.5f)
         + (a1 < 1.f ? 0.5f * d1 * d1 : a1 - 0.5f)
         + (a2 < 1.f ? 0.5f * d2 * d2 : a2 - 0.5f)
         + (a3 < 1.f ? 0.5f * d3 * d3 : a3 - 0.5f);
}

__device__ __forceinline__ float lse2(float c0, float c1)
{
#pragma clang fp contract(off)
    float mm = fmaxf(c0, c1), mn = fminf(c0, c1);
    return mm + __logf(1.f + __expf(mn - mm));
}

// ---------------- K1: IoU + per-prior best + PRE-FIX losses + mine, all fused ----------
// grid (32 tiles, 32 batches) x 256 threads; each thread owns 4 CONSECUTIVE priors.
// NOTE: o is STAGGERED per lane (o = (it + lane%32) & 31). This is load-bearing:
// it spreads keys[o] atomics over 32 LDS addresses (2 lanes/addr = conflict-free).
// A wave-uniform o funnels 64-lane same-address DS atomics -> DS-pipe serialization
// (measured R5: kern1 44->95 us with VALUBusy unchanged).
__global__ __launch_bounds__(256) void kern1(
        const float* __restrict__ loc, const float* __restrict__ conf,
        const float* __restrict__ priors, const float* __restrict__ targets,
        float* __restrict__ mine, u64* __restrict__ bpk_part,
        float* __restrict__ part_sl1, float* __restrict__ part_cep, int* __restrict__ part_np,
        float* __restrict__ sl_tot, float* __restrict__ c_tot,
        int* __restrict__ np_tot, int* __restrict__ done_cnt)
{
#pragma clang fp contract(off)
    __shared__ __align__(16) float4 tbc[NO];   // truth corners
    __shared__ float ta[NO], tlab[NO];
    __shared__ u64 keys[NO];
    __shared__ float rs0[4], rs1[4];
    __shared__ int rc[4];
    const int b = blockIdx.y, x = blockIdx.x, tid = threadIdx.x;
    if (b == 0 && x == 0 && tid == 0) {        // init accumulators for kern3 (runs after us)
        *sl_tot = 0.f; *c_tot = 0.f; *np_tot = 0; *done_cnt = 0;
    }
    if (tid < NO * 5) {
        int o = tid / 5, c = tid % 5;
        float v = targets[b * NO * 5 + tid];
        if (c < 4) ((float*)&tbc[o])[c] = v; else tlab[o] = v;
    }
    if (tid < NO) keys[tid] = 0ull;
    __syncthreads();
    if (tid < NO) {
        float4 t = tbc[tid];
        ta[tid] = (t.z - t.x) * (t.w - t.y);
    }
    __syncthreads();

    const int p0 = x * 1024 + tid * 4;
    float4 pr[4];
    float px1[4], py1[4], px2[4], py2[4], ab[4];
#pragma unroll
    for (int j = 0; j < 4; ++j) {
        pr[j] = ((const float4*)priors)[p0 + j];
        px1[j] = pr[j].x - pr[j].z * 0.5f;
        py1[j] = pr[j].y - pr[j].w * 0.5f;
        px2[j] = pr[j].x + pr[j].z * 0.5f;
        py2[j] = pr[j].y + pr[j].w * 0.5f;
        ab[j]  = pr[j].z * pr[j].w;
    }
    // per-prior best truth as packed u64: (iou_bits << 6) | (63 - o)
    // max => largest iou, tie => smallest o (reference first-max argmax)
    u64 bk[4] = {0ull, 0ull, 0ull, 0ull};
    const int lane_o = tid & 31;   // stagger (see note above)
    for (int it = 0; it < NO; ++it) {
        const int o = (it + lane_o) & 31;
        float4 tt = tbc[o];
        float aa = ta[o];
        float iou4[4];
#pragma unroll
        for (int j = 0; j < 4; ++j) {
            float iou = iou_corners(px1[j], py1[j], px2[j], py2[j], ab[j],
                                    tt.x, tt.y, tt.z, tt.w, aa);
            iou4[j] = iou;
            u64 ko = ((u64)__float_as_uint(iou) << 6) | (u64)(63 - o);
            bk[j] = bk[j] > ko ? bk[j] : ko;
        }
        // per-truth best prior: cheap value-only filter, rare full path
        float vm = fmaxf(fmaxf(iou4[0], iou4[1]), fmaxf(iou4[2], iou4[3]));
        u64 cur = keys[o];
        if (__float_as_uint(vm) > (u32)(cur >> 32)) {
            float bi = iou4[3]; int bp = p0 + 3;
            if (iou4[2] >= bi) { bi = iou4[2]; bp = p0 + 2; }
            if (iou4[1] >= bi) { bi = iou4[1]; bp = p0 + 1; }
            if (iou4[0] >= bi) { bi = iou4[0]; bp = p0 + 0; }
            atomicMax(&keys[o], ((u64)__float_as_uint(bi) << 32) | (u64)(~(u32)bp));
        }
    }

    // ---- pre-fix losses straight from registers ----
    const size_t gbase = (size_t)b * NP + p0;
    float4 cfa = ((const float4*)conf)[gbase / 2];
    float4 cfb = ((const float4*)conf)[gbase / 2 + 1];
    float c0[4] = {cfa.x, cfa.z, cfb.x, cfb.z};
    float c1[4] = {cfa.y, cfa.w, cfb.y, cfb.w};
    float4 mout;
    float s_sl1 = 0.f, s_cep = 0.f;
    int np = 0;
#pragma unroll
    for (int j = 0; j < 4; ++j) {
        u32 vb = (u32)(bk[j] >> 6);
        float bv = __uint_as_float(vb);
        int o = 63 - (int)(bk[j] & 63);
        int cf = (bv < THRESH) ? 0 : ((int)tlab[o] + 1);
        bool pos = cf > 0;
        float4 ld = ((const float4*)loc)[gbase + j];
        float sl1 = smooth_l1_sum(ld, pr[j], tbc[o]);
        float ce = lse2(c0[j], c1[j]) - ((cf == 0) ? c0[j] : c1[j]);
        if (pos) { s_sl1 += sl1; s_cep += ce; np++; }
        ((float*)&mout)[j] = pos ? 0.f : ce;
    }
    ((float4*)mine)[gbase / 4] = mout;

#pragma unroll
    for (int m = 32; m; m >>= 1) {
        s_sl1 += __shfl_xor(s_sl1, m, 64);
        s_cep += __shfl_xor(s_cep, m, 64);
        np    += __shfl_xor(np, m, 64);
    }
    int lane = tid & 63, w = tid >> 6;
    if (lane == 0) { rs0[w] = s_sl1; rs1[w] = s_cep; rc[w] = np; }
    __syncthreads();
    if (tid == 0) {
        float t0 = 0.f, t1 = 0.f; int t2 = 0;
        for (int i = 0; i < 4; ++i) { t0 += rs0[i]; t1 += rs1[i]; t2 += rc[i]; }
        part_sl1[b * 32 + x] = t0;
        part_cep[b * 32 + x] = t1;
        part_np [b * 32 + x] = t2;
    }
    if (tid < NO) bpk_part[(b * 32 + x) * 32 + tid] = keys[tid];  // after the sync above
}

// ---------------- K3: fix + deltas + BISECTION top-k sum + finalize ---------------------
// one block per batch, 1024 threads (16 waves). No LDS histograms: k-th largest key
// found by binary search on the 32-bit float key with register compares only
// (R6 post-mortem: histogram pass 0 = same-address LDS atomic serialization, 827K
//  conflict cycles; bisection has zero LDS atomics).
__global__ __launch_bounds__(1024) void kern3(
        const float* __restrict__ loc, const float* __restrict__ conf,
        const float* __restrict__ priors, const float* __restrict__ targets,
        const u64* __restrict__ bpk_part, const float* __restrict__ mine,
        const float* __restrict__ part_sl1, const float* __restrict__ part_cep,
        const int* __restrict__ part_np,
        float* __restrict__ sl_tot, float* __restrict__ c_tot,
        int* __restrict__ np_tot, int* __restrict__ done_cnt,
        float* __restrict__ out)
{
#pragma clang fp contract(off)
    const int b = blockIdx.x, tid = threadIdx.x;
    const int wave = tid >> 6, lane = tid & 63;
    __shared__ __align__(16) float4 tbc[NO];
    __shared__ float tlab[NO], tas[NO];
    __shared__ u32 pp[NO];
    __shared__ u32 flags[1024];                 // 32768-bit mask of forced priors
    __shared__ u32 red[2][16];                  // double-buffered per-wave exchange
    __shared__ float rs[16];
    __shared__ int rc2[16];
    __shared__ float sh_sl1, sh_cep;
    __shared__ int sh_np, sh_k;

    if (tid < NO * 5) {
        int o = tid / 5, c = tid % 5;
        float v = targets[b * NO * 5 + tid];
        if (c < 4) ((float*)&tbc[o])[c] = v; else tlab[o] = v;
    }
    flags[tid] = 0u;

    const float* mb = mine + (size_t)b * NP;
    float v[32];
#pragma unroll
    for (int q = 0; q < 8; ++q) {
        float4 t4 = ((const float4*)mb)[q * 1024 + tid];
        v[4 * q] = t4.x; v[4 * q + 1] = t4.y; v[4 * q + 2] = t4.z; v[4 * q + 3] = t4.w;
    }
    __syncthreads();
    if (tid < NO) {
        float4 t = tbc[tid];
        tas[tid] = (t.z - t.x) * (t.w - t.y);
        // resolve per-truth best prior across the 32 x-tiles
        u64 key = 0ull;
        for (int xx = 0; xx < 32; ++xx) {
            u64 t2 = bpk_part[(b * 32 + xx) * 32 + tid];
            key = t2 > key ? t2 : key;
        }
        pp[tid] = (key >> 32) ? ~(u32)key : 0u;   // all-zero row => argmax = 0
    }
    __syncthreads();
    if (tid < NO) {
        const int o = tid;
        const u32 p = pp[o];
        float dsl1 = 0.f, dcep = 0.f; int dnp = 0;
        bool last = true;
        for (int o2 = o + 1; o2 < NO; ++o2)
            if (pp[o2] == p) { last = false; break; }   // later o overwrites same prior
        if (last) {
            float4 prr = ((const float4*)priors)[p];
            float px1 = prr.x - prr.z * 0.5f, py1 = prr.y - prr.w * 0.5f;
            float px2 = prr.x + prr.z * 0.5f, py2 = prr.y + prr.w * 0.5f;
            float ab = prr.z * prr.w;
            // pre-fix best truth for p (natural order, strict > == first-max)
            float bv = -1.f; int bo_ = 0;
            for (int o2 = 0; o2 < NO; ++o2) {
                float4 t2 = tbc[o2];
                float i2 = iou_corners(px1, py1, px2, py2, ab, t2.x, t2.y, t2.z, t2.w, tas[o2]);
                if (i2 > bv) { bv = i2; bo_ = o2; }
            }
            int cf_pre = (bv < THRESH) ? 0 : ((int)tlab[bo_] + 1);
            size_t gp = (size_t)b * NP + p;
            float4 ld = ((const float4*)loc)[gp];
            float2 c = ((const float2*)conf)[gp];
            float lse = lse2(c.x, c.y);
            int cf_new = (int)tlab[o] + 1;               // forced positive
            dsl1 = smooth_l1_sum(ld, prr, tbc[o]);
            dcep = lse - ((cf_new == 0) ? c.x : c.y);
            dnp = 1;
            if (cf_pre > 0) {                            // remove pre-fix contribution
                dsl1 -= smooth_l1_sum(ld, prr, tbc[bo_]);
                dcep -= lse - ((cf_pre == 0) ? c.x : c.y);
                dnp = 0;
            }
            atomicOr(&flags[p >> 5], 1u << (p & 31));
        }
        // batch stats: 32 kern1 partials + this lane's delta
        float a = part_sl1[b * 32 + o] + dsl1;
        float d = part_cep[b * 32 + o] + dcep;
        int   n = part_np [b * 32 + o] + dnp;
#pragma unroll
        for (int m = 16; m; m >>= 1) {
            a += __shfl_xor(a, m, 32);
            d += __shfl_xor(d, m, 32);
            n += __shfl_xor(n, m, 32);
        }
        if (o == 0) {
            sh_sl1 = a; sh_cep = d; sh_np = n;
            sh_k = min(7 * n, NP - 1);
        }
    }
    __syncthreads();
    // zero forced priors in-register (they become pos => mine 0)
#pragma unroll
    for (int q = 0; q < 8; ++q) {
        u32 word = flags[q * 128 + (tid >> 3)];
#pragma unroll
        for (int c = 0; c < 4; ++c)
            if ((word >> (((tid & 7) << 2) + c)) & 1u) v[4 * q + c] = 0.f;
    }
    const int k = sh_k;
    float topk = 0.f;
    if (k > 0) {
        // ---- block max key (upper bisection bound) ----
        u32 mx = 0;
#pragma unroll
        for (int j = 0; j < 32; ++j) mx = max(mx, __float_as_uint(v[j]));
#pragma unroll
        for (int m = 32; m; m >>= 1) mx = max(mx, (u32)__shfl_xor((int)mx, m, 64));
        if (lane == 0) red[0][wave] = mx;
        __syncthreads();
        {
            u32 t = red[0][lane & 15];
#pragma unroll
            for (int m = 8; m; m >>= 1) t = max(t, (u32)__shfl_xor((int)t, m, 64));
            mx = t;   // every lane now has block max
        }
        __syncthreads();
        // ---- bisection: T* = min t in [0,mx] with count(key > t) < k ----
        // (count(mx)=0 < k, so invariant holds; all threads compute identical lo/hi)
        u32 lo = 0, hi = mx;
        int parity = 0;
        while (lo < hi) {
            u32 mid = lo + ((hi - lo) >> 1);
            int c = 0;
#pragma unroll
            for (int j = 0; j < 32; ++j) c += (__float_as_uint(v[j]) > mid) ? 1 : 0;
#pragma unroll
            for (int m = 32; m; m >>= 1) c += __shfl_xor(c, m, 64);
            if (lane == 0) red[parity][wave] = (u32)c;
            __syncthreads();          // double-buffered: one barrier per round
            u32 t = red[parity][lane & 15];
#pragma unroll
            for (int m = 8; m; m >>= 1) t += (u32)__shfl_xor((int)t, m, 64);
            if ((int)t < k) hi = mid; else lo = mid + 1;
            parity ^= 1;
        }
        const u32 T = lo;                       // exact k-th largest key
        const float tval = __uint_as_float(T);
        float s = 0.f; int c2 = 0;
#pragma unroll
        for (int j = 0; j < 32; ++j) {
            if (__float_as_uint(v[j]) > T) { s += v[j]; c2++; }
        }
#pragma unroll
        for (int m = 32; m; m >>= 1) {
            s  += __shfl_xor(s, m, 64);
            c2 += __shfl_xor(c2, m, 64);
        }
        __syncthreads();                        // red/rs reuse safety
        if (lane == 0) { rs[wave] = s; rc2[wave] = c2; }
        __syncthreads();
        if (tid == 0) {
            float st = 0.f; int ct = 0;
            for (int i = 0; i < 16; ++i) { st += rs[i]; ct += rc2[i]; }
            topk = st + (float)(k - ct) * tval; // ties at T fill remaining slots
        }
    }
    if (tid == 0) {                            // accumulate + last-block finalize
        atomicAdd(sl_tot, sh_sl1);
        atomicAdd(c_tot, sh_cep + topk);
        atomicAdd(np_tot, sh_np);
        __threadfence();
        int d = atomicAdd(done_cnt, 1);
        if (d == NB - 1) {
            float sl = atomicAdd(sl_tot, 0.f);   // coherent reads incl. all contributions
            float cc = atomicAdd(c_tot, 0.f);
            int   np = atomicAdd(np_tot, 0);
            float N = fmaxf((float)np, 1.f);
            out[0] = sl / N;
            out[1] = cc / N;
        }
    }
}

extern "C" void kernel_launch(void* const* d_in, const int* in_sizes, int n_in,
                              void* d_out, int out_size, void* d_ws, size_t ws_size,
                              hipStream_t stream) {
    const float* loc     = (const float*)d_in[0];   // (B,P,4)
    const float* conf    = (const float*)d_in[1];   // (B,P,2)
    const float* priors  = (const float*)d_in[2];   // (P,4)
    const float* targets = (const float*)d_in[3];   // (B,O,5)
    float* out = (float*)d_out;

    char* ws = (char*)d_ws;
    float* mine     = (float*)ws;                       // 4 MB, fully written by K1
    u64*   bpk_part = (u64*)(ws + 4194304);             // 256 KB [b][x][o], fully written by K1
    float* part_sl1 = (float*)(ws + 4456448);           // [b][32] kern1 partials
    float* part_cep = (float*)(ws + 4460544);
    int*   part_np  = (int*)(ws + 4464640);
    float* sl_tot   = (float*)(ws + 4468736);           // zero-inited by kern1 block (0,0)
    float* c_tot    = (float*)(ws + 4468740);
    int*   np_tot   = (int*)(ws + 4468744);
    int*   done_cnt = (int*)(ws + 4468748);

    dim3 g1(32, NB);
    kern1<<<g1, 256, 0, stream>>>(loc, conf, priors, targets, mine, bpk_part,
                                  part_sl1, part_cep, part_np,
                                  sl_tot, c_tot, np_tot, done_cnt);
    kern3<<<NB, 1024, 0, stream>>>(loc, conf, priors, targets, bpk_part, mine,
                                   part_sl1, part_cep, part_np,
                                   sl_tot, c_tot, np_tot, done_cnt, out);
}

// Round 8
// 136.550 us; speedup vs baseline: 1.4789x; 1.0963x over previous
//
#include <hip/hip_runtime.h>
#include <stdint.h>

#define NB 32
#define NP 32768
#define NO 32
#define THRESH 0.35f

typedef unsigned long long u64;
typedef unsigned int u32;

// fast IoU from prior corners + truth corners. kern1's additions and kern3's
// delta-subtractions must cancel bit-exactly, so BOTH use this helper.
__device__ __forceinline__ float iou_corners(float px1, float py1, float px2, float py2, float ab,
                                             float tx1, float ty1, float tx2, float ty2, float aa)
{
#pragma clang fp contract(off)
    float iw = fminf(tx2, px2) - fmaxf(tx1, px1);
    float ih = fminf(ty2, py2) - fmaxf(ty1, py1);
    iw = fmaxf(iw, 0.f); ih = fmaxf(ih, 0.f);
    float inter = iw * ih;
    return __fdividef(inter, aa + ab - inter);
}

// smooth-L1 of (loc - encode(truth, prior)), summed over 4 coords
__device__ __forceinline__ float smooth_l1_sum(float4 ld, float4 pr, float4 tt)
{
#pragma clang fp contract(off)
    float g0 = __fdividef((tt.x + tt.z) * 0.5f - pr.x, 0.1f * pr.z);
    float g1 = __fdividef((tt.y + tt.w) * 0.5f - pr.y, 0.1f * pr.w);
    float g2 = __logf(__fdividef(tt.z - tt.x, pr.z)) * 5.0f;
    float g3 = __logf(__fdividef(tt.w - tt.y, pr.w)) * 5.0f;
    float d0 = ld.x - g0, d1 = ld.y - g1, d2 = ld.z - g2, d3 = ld.w - g3;
    float a0 = fabsf(d0), a1 = fabsf(d1), a2 = fabsf(d2), a3 = fabsf(d3);
    return (a0 < 1.f ? 0.5f * d0 * d0 : a0 - 0.5f)
         + (a1 < 1.f ? 0.5f * d1 * d1 : a1 - 0.5f)
         + (a2 < 1.f ? 0.5f * d2 * d2 : a2 - 0.5f)
         + (a3 < 1.f ? 0.5f * d3 * d3 : a3 - 0.5f);
}

__device__ __forceinline__ float lse2(float c0, float c1)
{
#pragma clang fp contract(off)
    float mm = fmaxf(c0, c1), mn = fminf(c0, c1);
    return mm + __logf(1.f + __expf(mn - mm));
}

// ---------------- K1: IoU + per-prior best + PRE-FIX losses + mine, all fused ----------
// grid (32 tiles, 32 batches) x 256 threads; each thread owns 4 CONSECUTIVE priors.
// NOTE: o is STAGGERED per lane (o = (it + lane%32) & 31). This is load-bearing:
// it spreads keys[o] atomics over 32 LDS addresses (2 lanes/addr = conflict-free).
// A wave-uniform o funnels 64-lane same-address DS atomics -> DS-pipe serialization
// (measured R5: kern1 44->95 us with VALUBusy unchanged).
__global__ __launch_bounds__(256) void kern1(
        const float* __restrict__ loc, const float* __restrict__ conf,
        const float* __restrict__ priors, const float* __restrict__ targets,
        float* __restrict__ mine, u64* __restrict__ bpk_part,
        float* __restrict__ part_sl1, float* __restrict__ part_cep, int* __restrict__ part_np,
        float* __restrict__ sl_tot, float* __restrict__ c_tot,
        int* __restrict__ np_tot, int* __restrict__ done_cnt)
{
#pragma clang fp contract(off)
    __shared__ __align__(16) float4 tbc[NO];   // truth corners
    __shared__ float ta[NO], tlab[NO];
    __shared__ u64 keys[NO];
    __shared__ float rs0[4], rs1[4];
    __shared__ int rc[4];
    const int b = blockIdx.y, x = blockIdx.x, tid = threadIdx.x;
    if (b == 0 && x == 0 && tid == 0) {        // init accumulators for kern3 (runs after us)
        *sl_tot = 0.f; *c_tot = 0.f; *np_tot = 0; *done_cnt = 0;
    }
    if (tid < NO * 5) {
        int o = tid / 5, c = tid % 5;
        float v = targets[b * NO * 5 + tid];
        if (c < 4) ((float*)&tbc[o])[c] = v; else tlab[o] = v;
    }
    if (tid < NO) keys[tid] = 0ull;
    __syncthreads();
    if (tid < NO) {
        float4 t = tbc[tid];
        ta[tid] = (t.z - t.x) * (t.w - t.y);
    }
    __syncthreads();

    const int p0 = x * 1024 + tid * 4;
    float4 pr[4];
    float px1[4], py1[4], px2[4], py2[4], ab[4];
#pragma unroll
    for (int j = 0; j < 4; ++j) {
        pr[j] = ((const float4*)priors)[p0 + j];
        px1[j] = pr[j].x - pr[j].z * 0.5f;
        py1[j] = pr[j].y - pr[j].w * 0.5f;
        px2[j] = pr[j].x + pr[j].z * 0.5f;
        py2[j] = pr[j].y + pr[j].w * 0.5f;
        ab[j]  = pr[j].z * pr[j].w;
    }
    // per-prior best truth as packed u64: (iou_bits << 6) | (63 - o)
    // max => largest iou, tie => smallest o (reference first-max argmax)
    u64 bk[4] = {0ull, 0ull, 0ull, 0ull};
    const int lane_o = tid & 31;   // stagger (see note above)
    for (int it = 0; it < NO; ++it) {
        const int o = (it + lane_o) & 31;
        float4 tt = tbc[o];
        float aa = ta[o];
        float iou4[4];
#pragma unroll
        for (int j = 0; j < 4; ++j) {
            float iou = iou_corners(px1[j], py1[j], px2[j], py2[j], ab[j],
                                    tt.x, tt.y, tt.z, tt.w, aa);
            iou4[j] = iou;
            u64 ko = ((u64)__float_as_uint(iou) << 6) | (u64)(63 - o);
            bk[j] = bk[j] > ko ? bk[j] : ko;
        }
        // per-truth best prior: cheap value-only filter, rare full path
        float vm = fmaxf(fmaxf(iou4[0], iou4[1]), fmaxf(iou4[2], iou4[3]));
        u64 cur = keys[o];
        if (__float_as_uint(vm) > (u32)(cur >> 32)) {
            float bi = iou4[3]; int bp = p0 + 3;
            if (iou4[2] >= bi) { bi = iou4[2]; bp = p0 + 2; }
            if (iou4[1] >= bi) { bi = iou4[1]; bp = p0 + 1; }
            if (iou4[0] >= bi) { bi = iou4[0]; bp = p0 + 0; }
            atomicMax(&keys[o], ((u64)__float_as_uint(bi) << 32) | (u64)(~(u32)bp));
        }
    }

    // ---- pre-fix losses straight from registers ----
    const size_t gbase = (size_t)b * NP + p0;
    float4 cfa = ((const float4*)conf)[gbase / 2];
    float4 cfb = ((const float4*)conf)[gbase / 2 + 1];
    float c0[4] = {cfa.x, cfa.z, cfb.x, cfb.z};
    float c1[4] = {cfa.y, cfa.w, cfb.y, cfb.w};
    float4 mout;
    float s_sl1 = 0.f, s_cep = 0.f;
    int np = 0;
#pragma unroll
    for (int j = 0; j < 4; ++j) {
        u32 vb = (u32)(bk[j] >> 6);
        float bv = __uint_as_float(vb);
        int o = 63 - (int)(bk[j] & 63);
        int cf = (bv < THRESH) ? 0 : ((int)tlab[o] + 1);
        bool pos = cf > 0;
        float4 ld = ((const float4*)loc)[gbase + j];
        float sl1 = smooth_l1_sum(ld, pr[j], tbc[o]);
        float ce = lse2(c0[j], c1[j]) - ((cf == 0) ? c0[j] : c1[j]);
        if (pos) { s_sl1 += sl1; s_cep += ce; np++; }
        ((float*)&mout)[j] = pos ? 0.f : ce;
    }
    ((float4*)mine)[gbase / 4] = mout;

#pragma unroll
    for (int m = 32; m; m >>= 1) {
        s_sl1 += __shfl_xor(s_sl1, m, 64);
        s_cep += __shfl_xor(s_cep, m, 64);
        np    += __shfl_xor(np, m, 64);
    }
    int lane = tid & 63, w = tid >> 6;
    if (lane == 0) { rs0[w] = s_sl1; rs1[w] = s_cep; rc[w] = np; }
    __syncthreads();
    if (tid == 0) {
        float t0 = 0.f, t1 = 0.f; int t2 = 0;
        for (int i = 0; i < 4; ++i) { t0 += rs0[i]; t1 += rs1[i]; t2 += rc[i]; }
        part_sl1[b * 32 + x] = t0;
        part_cep[b * 32 + x] = t1;
        part_np [b * 32 + x] = t2;
    }
    if (tid < NO) bpk_part[(b * 32 + x) * 32 + tid] = keys[tid];  // after the sync above
}

// ---------------- K3: fix + deltas + column-per-lane radix-select top-k + finalize ------
// one block per batch, 1024 threads (16 waves). Top-k via 4x 8-bit radix passes with
// hist[256][65]: lane l always writes column l -> within-wave banks (bin+l)%32 cover
// all 32 banks regardless of bin concentration (R4's failure mode), and only 4 passes
// of 1 barrier-chain each (R6 bisection's failure mode: ~31 serial barrier rounds).
#define HCOL 65
__global__ __launch_bounds__(1024) void kern3(
        const float* __restrict__ loc, const float* __restrict__ conf,
        const float* __restrict__ priors, const float* __restrict__ targets,
        const u64* __restrict__ bpk_part, const float* __restrict__ mine,
        const float* __restrict__ part_sl1, const float* __restrict__ part_cep,
        const int* __restrict__ part_np,
        float* __restrict__ sl_tot, float* __restrict__ c_tot,
        int* __restrict__ np_tot, int* __restrict__ done_cnt,
        float* __restrict__ out)
{
#pragma clang fp contract(off)
    const int b = blockIdx.x, tid = threadIdx.x;
    const int wave = tid >> 6, lane = tid & 63;
    __shared__ __align__(16) float4 tbc[NO];
    __shared__ float tlab[NO], tas[NO];
    __shared__ u32 pp[NO];
    __shared__ u32 flags[1024];                 // 32768-bit mask of forced priors
    __shared__ int hist[256 * HCOL];            // 66.6 KB column-per-lane histogram
    __shared__ int total[256];
    __shared__ float rs[16];
    __shared__ int rc2[16];
    __shared__ float sh_sl1, sh_cep;
    __shared__ int sh_np, sh_k, sh_kk;
    __shared__ u32 sh_prefix;

    if (tid < NO * 5) {
        int o = tid / 5, c = tid % 5;
        float v = targets[b * NO * 5 + tid];
        if (c < 4) ((float*)&tbc[o])[c] = v; else tlab[o] = v;
    }
    flags[tid] = 0u;

    const float* mb = mine + (size_t)b * NP;
    float v[32];
#pragma unroll
    for (int q = 0; q < 8; ++q) {
        float4 t4 = ((const float4*)mb)[q * 1024 + tid];
        v[4 * q] = t4.x; v[4 * q + 1] = t4.y; v[4 * q + 2] = t4.z; v[4 * q + 3] = t4.w;
    }
    __syncthreads();
    if (tid < NO) {
        float4 t = tbc[tid];
        tas[tid] = (t.z - t.x) * (t.w - t.y);
        // resolve per-truth best prior across the 32 x-tiles
        u64 key = 0ull;
        for (int xx = 0; xx < 32; ++xx) {
            u64 t2 = bpk_part[(b * 32 + xx) * 32 + tid];
            key = t2 > key ? t2 : key;
        }
        pp[tid] = (key >> 32) ? ~(u32)key : 0u;   // all-zero row => argmax = 0
    }
    __syncthreads();
    if (tid < NO) {
        const int o = tid;
        const u32 p = pp[o];
        float dsl1 = 0.f, dcep = 0.f; int dnp = 0;
        bool last = true;
        for (int o2 = o + 1; o2 < NO; ++o2)
            if (pp[o2] == p) { last = false; break; }   // later o overwrites same prior
        if (last) {
            float4 prr = ((const float4*)priors)[p];
            float px1 = prr.x - prr.z * 0.5f, py1 = prr.y - prr.w * 0.5f;
            float px2 = prr.x + prr.z * 0.5f, py2 = prr.y + prr.w * 0.5f;
            float ab = prr.z * prr.w;
            // pre-fix best truth for p (natural order, strict > == first-max)
            float bv = -1.f; int bo_ = 0;
            for (int o2 = 0; o2 < NO; ++o2) {
                float4 t2 = tbc[o2];
                float i2 = iou_corners(px1, py1, px2, py2, ab, t2.x, t2.y, t2.z, t2.w, tas[o2]);
                if (i2 > bv) { bv = i2; bo_ = o2; }
            }
            int cf_pre = (bv < THRESH) ? 0 : ((int)tlab[bo_] + 1);
            size_t gp = (size_t)b * NP + p;
            float4 ld = ((const float4*)loc)[gp];
            float2 c = ((const float2*)conf)[gp];
            float lse = lse2(c.x, c.y);
            int cf_new = (int)tlab[o] + 1;               // forced positive
            dsl1 = smooth_l1_sum(ld, prr, tbc[o]);
            dcep = lse - ((cf_new == 0) ? c.x : c.y);
            dnp = 1;
            if (cf_pre > 0) {                            // remove pre-fix contribution
                dsl1 -= smooth_l1_sum(ld, prr, tbc[bo_]);
                dcep -= lse - ((cf_pre == 0) ? c.x : c.y);
                dnp = 0;
            }
            atomicOr(&flags[p >> 5], 1u << (p & 31));
        }
        // batch stats: 32 kern1 partials + this lane's delta
        float a = part_sl1[b * 32 + o] + dsl1;
        float d = part_cep[b * 32 + o] + dcep;
        int   n = part_np [b * 32 + o] + dnp;
#pragma unroll
        for (int m = 16; m; m >>= 1) {
            a += __shfl_xor(a, m, 32);
            d += __shfl_xor(d, m, 32);
            n += __shfl_xor(n, m, 32);
        }
        if (o == 0) {
            sh_sl1 = a; sh_cep = d; sh_np = n;
            sh_k = min(7 * n, NP - 1); sh_kk = sh_k; sh_prefix = 0u;
        }
    }
    __syncthreads();
    // zero forced priors in-register (they become pos => mine 0)
#pragma unroll
    for (int q = 0; q < 8; ++q) {
        u32 word = flags[q * 128 + (tid >> 3)];
#pragma unroll
        for (int c = 0; c < 4; ++c)
            if ((word >> (((tid & 7) << 2) + c)) & 1u) v[4 * q + c] = 0.f;
    }
    const int k = sh_k;
    float topk = 0.f;
    if (k > 0) {
        for (int pass = 0; pass < 4; ++pass) {
            for (int i = tid; i < 256 * HCOL; i += 1024) hist[i] = 0;
            __syncthreads();
            const int shift = 24 - 8 * pass;
            const u32 pfx = sh_prefix;
#pragma unroll 8
            for (int j = 0; j < 32; ++j) {
                u32 kb = __float_as_uint(v[j]);
                if ((u32)(((u64)kb) >> (shift + 8)) == pfx)   // 64-bit shift: defined at 32
                    atomicAdd(&hist[((kb >> shift) & 255) * HCOL + lane], 1);
            }
            __syncthreads();
            {   // reduce 64 columns per bin: thread t sums quarter (t&3) of bin (t>>2)
                int bin = tid >> 2, q = tid & 3;
                const int base = bin * HCOL + q * 16;
                int s = 0;
#pragma unroll
                for (int i = 0; i < 16; ++i) s += hist[base + i];
                s += __shfl_xor(s, 2, 64);
                s += __shfl_xor(s, 1, 64);
                if (q == 0) total[bin] = s;
            }
            __syncthreads();
            if (tid < 64) {                  // suffix-scan select over 256 bins
                int4 h4 = ((const int4*)total)[tid];
                int s3 = h4.w, s2 = h4.z + s3, s1 = h4.y + s2, s0 = h4.x + s1;
                int acc = s0;
#pragma unroll
                for (int off = 1; off < 64; off <<= 1) {
                    int u = __shfl_down(acc, off, 64);
                    if (tid + off < 64) acc += u;
                }
                int excl = acc - s0;
                int kk = sh_kk;
                int cand = -1, nkk = 0;
                if (excl + s3 >= kk)      { cand = 4 * tid + 3; nkk = kk - excl; }
                else if (excl + s2 >= kk) { cand = 4 * tid + 2; nkk = kk - excl - s3; }
                else if (excl + s1 >= kk) { cand = 4 * tid + 1; nkk = kk - excl - s2; }
                else if (excl + s0 >= kk) { cand = 4 * tid + 0; nkk = kk - excl - s1; }
                int cmax = cand;
#pragma unroll
                for (int off = 1; off < 64; off <<= 1) cmax = max(cmax, __shfl_xor(cmax, off, 64));
                if (cand >= 0 && cand == cmax) {
                    sh_prefix = (pfx << 8) | (u32)(cand & 255);
                    sh_kk = nkk;
                }
            }
            __syncthreads();
        }
        const u32 T = sh_prefix;                // exact k-th largest key
        const float tval = __uint_as_float(T);
        float s = 0.f; int c2 = 0;
#pragma unroll
        for (int j = 0; j < 32; ++j) {
            if (__float_as_uint(v[j]) > T) { s += v[j]; c2++; }
        }
#pragma unroll
        for (int m = 32; m; m >>= 1) {
            s  += __shfl_xor(s, m, 64);
            c2 += __shfl_xor(c2, m, 64);
        }
        if (lane == 0) { rs[wave] = s; rc2[wave] = c2; }
        __syncthreads();
        if (tid == 0) {
            float st = 0.f; int ct = 0;
            for (int i = 0; i < 16; ++i) { st += rs[i]; ct += rc2[i]; }
            topk = st + (float)(k - ct) * tval; // ties at T fill remaining slots
        }
    }
    if (tid == 0) {                            // accumulate + last-block finalize
        atomicAdd(sl_tot, sh_sl1);
        atomicAdd(c_tot, sh_cep + topk);
        atomicAdd(np_tot, sh_np);
        __threadfence();
        int d = atomicAdd(done_cnt, 1);
        if (d == NB - 1) {
            float sl = atomicAdd(sl_tot, 0.f);   // coherent reads incl. all contributions
            float cc = atomicAdd(c_tot, 0.f);
            int   np = atomicAdd(np_tot, 0);
            float N = fmaxf((float)np, 1.f);
            out[0] = sl / N;
            out[1] = cc / N;
        }
    }
}

extern "C" void kernel_launch(void* const* d_in, const int* in_sizes, int n_in,
                              void* d_out, int out_size, void* d_ws, size_t ws_size,
                              hipStream_t stream) {
    const float* loc     = (const float*)d_in[0];   // (B,P,4)
    const float* conf    = (const float*)d_in[1];   // (B,P,2)
    const float* priors  = (const float*)d_in[2];   // (P,4)
    const float* targets = (const float*)d_in[3];   // (B,O,5)
    float* out = (float*)d_out;

    char* ws = (char*)d_ws;
    float* mine     = (float*)ws;                       // 4 MB, fully written by K1
    u64*   bpk_part = (u64*)(ws + 4194304);             // 256 KB [b][x][o], fully written by K1
    float* part_sl1 = (float*)(ws + 4456448);           // [b][32] kern1 partials
    float* part_cep = (float*)(ws + 4460544);
    int*   part_np  = (int*)(ws + 4464640);
    float* sl_tot   = (float*)(ws + 4468736);           // zero-inited by kern1 block (0,0)
    float* c_tot    = (float*)(ws + 4468740);
    int*   np_tot   = (int*)(ws + 4468744);
    int*   done_cnt = (int*)(ws + 4468748);

    dim3 g1(32, NB);
    kern1<<<g1, 256, 0, stream>>>(loc, conf, priors, targets, mine, bpk_part,
                                  part_sl1, part_cep, part_np,
                                  sl_tot, c_tot, np_tot, done_cnt);
    kern3<<<NB, 1024, 0, stream>>>(loc, conf, priors, targets, bpk_part, mine,
                                   part_sl1, part_cep, part_np,
                                   sl_tot, c_tot, np_tot, done_cnt, out);
}

// Round 9
// 127.178 us; speedup vs baseline: 1.5879x; 1.0737x over previous
//
#include <hip/hip_runtime.h>
#include <stdint.h>

#define NB 32
#define NP 32768
#define NO 32
#define THRESH 0.35f
#define NT1 64          // kern1 x-tiles (512 priors each)

typedef unsigned long long u64;
typedef unsigned int u32;

// fast IoU from prior corners + truth corners. kern1's additions and kern3's
// delta-subtractions must cancel bit-exactly, so BOTH use this helper.
__device__ __forceinline__ float iou_corners(float px1, float py1, float px2, float py2, float ab,
                                             float tx1, float ty1, float tx2, float ty2, float aa)
{
#pragma clang fp contract(off)
    float iw = fminf(tx2, px2) - fmaxf(tx1, px1);
    float ih = fminf(ty2, py2) - fmaxf(ty1, py1);
    iw = fmaxf(iw, 0.f); ih = fmaxf(ih, 0.f);
    float inter = iw * ih;
    return __fdividef(inter, aa + ab - inter);
}

// smooth-L1 of (loc - encode(truth, prior)), summed over 4 coords
__device__ __forceinline__ float smooth_l1_sum(float4 ld, float4 pr, float4 tt)
{
#pragma clang fp contract(off)
    float g0 = __fdividef((tt.x + tt.z) * 0.5f - pr.x, 0.1f * pr.z);
    float g1 = __fdividef((tt.y + tt.w) * 0.5f - pr.y, 0.1f * pr.w);
    float g2 = __logf(__fdividef(tt.z - tt.x, pr.z)) * 5.0f;
    float g3 = __logf(__fdividef(tt.w - tt.y, pr.w)) * 5.0f;
    float d0 = ld.x - g0, d1 = ld.y - g1, d2 = ld.z - g2, d3 = ld.w - g3;
    float a0 = fabsf(d0), a1 = fabsf(d1), a2 = fabsf(d2), a3 = fabsf(d3);
    return (a0 < 1.f ? 0.5f * d0 * d0 : a0 - 0.5f)
         + (a1 < 1.f ? 0.5f * d1 * d1 : a1 - 0.5f)
         + (a2 < 1.f ? 0.5f * d2 * d2 : a2 - 0.5f)
         + (a3 < 1.f ? 0.5f * d3 * d3 : a3 - 0.5f);
}

__device__ __forceinline__ float lse2(float c0, float c1)
{
#pragma clang fp contract(off)
    float mm = fmaxf(c0, c1), mn = fminf(c0, c1);
    return mm + __logf(1.f + __expf(mn - mm));
}

// ---------------- K1: IoU + per-prior best + PRE-FIX losses + mine, all fused ----------
// grid (64 tiles, 32 batches) x 256 threads; each thread owns 2 CONSECUTIVE priors.
// 2048 blocks -> 8 blocks/CU -> 32 waves/CU (max occupancy; VGPR=32 permits it).
// NOTE: o is STAGGERED per lane (o = (it + lane%32) & 31). Load-bearing: spreads
// keys[o] reads/atomics over 32 LDS addresses (2 lanes/addr = conflict-free).
// Wave-uniform o funnels 64-lane same-address DS atomics -> DS-pipe serialization
// (measured R5: kern1 44->95 us with VALUBusy unchanged).
__global__ __launch_bounds__(256) void kern1(
        const float* __restrict__ loc, const float* __restrict__ conf,
        const float* __restrict__ priors, const float* __restrict__ targets,
        float* __restrict__ mine, u64* __restrict__ bpk_part,
        float* __restrict__ part_sl1, float* __restrict__ part_cep, int* __restrict__ part_np,
        float* __restrict__ sl_tot, float* __restrict__ c_tot,
        int* __restrict__ np_tot, int* __restrict__ done_cnt)
{
#pragma clang fp contract(off)
    __shared__ __align__(16) float4 tbc[NO];   // truth corners
    __shared__ float ta[NO], tlab[NO];
    __shared__ u64 keys[NO];
    __shared__ float rs0[4], rs1[4];
    __shared__ int rc[4];
    const int b = blockIdx.y, x = blockIdx.x, tid = threadIdx.x;
    if (b == 0 && x == 0 && tid == 0) {        // init accumulators for kern3 (runs after us)
        *sl_tot = 0.f; *c_tot = 0.f; *np_tot = 0; *done_cnt = 0;
    }
    if (tid < NO * 5) {
        int o = tid / 5, c = tid % 5;
        float v = targets[b * NO * 5 + tid];
        if (c < 4) ((float*)&tbc[o])[c] = v; else tlab[o] = v;
    }
    if (tid < NO) keys[tid] = 0ull;
    __syncthreads();
    if (tid < NO) {
        float4 t = tbc[tid];
        ta[tid] = (t.z - t.x) * (t.w - t.y);
    }
    __syncthreads();

    const int p0 = x * 512 + tid * 2;
    float4 pr[2];
    float px1[2], py1[2], px2[2], py2[2], ab[2];
#pragma unroll
    for (int j = 0; j < 2; ++j) {
        pr[j] = ((const float4*)priors)[p0 + j];
        px1[j] = pr[j].x - pr[j].z * 0.5f;
        py1[j] = pr[j].y - pr[j].w * 0.5f;
        px2[j] = pr[j].x + pr[j].z * 0.5f;
        py2[j] = pr[j].y + pr[j].w * 0.5f;
        ab[j]  = pr[j].z * pr[j].w;
    }
    // per-prior best truth as packed u64: (iou_bits << 6) | (63 - o)
    // max => largest iou, tie => smallest o (reference first-max argmax)
    u64 bk[2] = {0ull, 0ull};
    const int lane_o = tid & 31;   // stagger (see note above)
    for (int it = 0; it < NO; ++it) {
        const int o = (it + lane_o) & 31;
        float4 tt = tbc[o];
        float aa = ta[o];
        float iou2[2];
#pragma unroll
        for (int j = 0; j < 2; ++j) {
            float iou = iou_corners(px1[j], py1[j], px2[j], py2[j], ab[j],
                                    tt.x, tt.y, tt.z, tt.w, aa);
            iou2[j] = iou;
            u64 ko = ((u64)__float_as_uint(iou) << 6) | (u64)(63 - o);
            bk[j] = bk[j] > ko ? bk[j] : ko;
        }
        // per-truth best prior: cheap value-only filter, rare full path
        float vm = fmaxf(iou2[0], iou2[1]);
        u64 cur = keys[o];
        if (__float_as_uint(vm) > (u32)(cur >> 32)) {
            float bi = iou2[1]; int bp = p0 + 1;
            if (iou2[0] >= bi) { bi = iou2[0]; bp = p0; }
            atomicMax(&keys[o], ((u64)__float_as_uint(bi) << 32) | (u64)(~(u32)bp));
        }
    }

    // ---- pre-fix losses straight from registers ----
    const size_t gbase = (size_t)b * NP + p0;
    float4 cf = ((const float4*)conf)[gbase >> 1];
    float c0[2] = {cf.x, cf.z};
    float c1[2] = {cf.y, cf.w};
    float2 mout;
    float s_sl1 = 0.f, s_cep = 0.f;
    int np = 0;
#pragma unroll
    for (int j = 0; j < 2; ++j) {
        u32 vb = (u32)(bk[j] >> 6);
        float bv = __uint_as_float(vb);
        int o = 63 - (int)(bk[j] & 63);
        int cfv = (bv < THRESH) ? 0 : ((int)tlab[o] + 1);
        bool pos = cfv > 0;
        float4 ld = ((const float4*)loc)[gbase + j];
        float sl1 = smooth_l1_sum(ld, pr[j], tbc[o]);
        float ce = lse2(c0[j], c1[j]) - ((cfv == 0) ? c0[j] : c1[j]);
        if (pos) { s_sl1 += sl1; s_cep += ce; np++; }
        ((float*)&mout)[j] = pos ? 0.f : ce;
    }
    ((float2*)mine)[gbase >> 1] = mout;

#pragma unroll
    for (int m = 32; m; m >>= 1) {
        s_sl1 += __shfl_xor(s_sl1, m, 64);
        s_cep += __shfl_xor(s_cep, m, 64);
        np    += __shfl_xor(np, m, 64);
    }
    int lane = tid & 63, w = tid >> 6;
    if (lane == 0) { rs0[w] = s_sl1; rs1[w] = s_cep; rc[w] = np; }
    __syncthreads();
    if (tid == 0) {
        float t0 = 0.f, t1 = 0.f; int t2 = 0;
        for (int i = 0; i < 4; ++i) { t0 += rs0[i]; t1 += rs1[i]; t2 += rc[i]; }
        part_sl1[b * NT1 + x] = t0;
        part_cep[b * NT1 + x] = t1;
        part_np [b * NT1 + x] = t2;
    }
    if (tid < NO) bpk_part[(b * NT1 + x) * 32 + tid] = keys[tid];  // after the sync above
}

// ---------------- K3: fix + deltas + column-per-lane radix-select top-k + finalize ------
// one block per batch, 1024 threads (16 waves). hist[256][33], column = lane&31:
// within-wave banks (bin+lane)%32 cover all 32 banks regardless of bin concentration
// (R4 failure mode); only 2-way same-address aliasing on atomics. Pass-0 histogram is
// hoisted BEFORE the fix phase (pre-fix values + <=32 sub/add corrections) to shorten
// the serial barrier chain (R8: kern3 ~31 us, clear+barrier dominated).
#define HCOL 33
__global__ __launch_bounds__(1024) void kern3(
        const float* __restrict__ loc, const float* __restrict__ conf,
        const float* __restrict__ priors, const float* __restrict__ targets,
        const u64* __restrict__ bpk_part, const float* __restrict__ mine,
        const float* __restrict__ part_sl1, const float* __restrict__ part_cep,
        const int* __restrict__ part_np,
        float* __restrict__ sl_tot, float* __restrict__ c_tot,
        int* __restrict__ np_tot, int* __restrict__ done_cnt,
        float* __restrict__ out)
{
#pragma clang fp contract(off)
    const int b = blockIdx.x, tid = threadIdx.x;
    const int wave = tid >> 6, lane = tid & 63;
    const int cl = lane & 31;                   // histogram column
    __shared__ __align__(16) float4 tbc[NO];
    __shared__ float tlab[NO], tas[NO];
    __shared__ u32 pp[NO];
    __shared__ u32 flags[1024];                 // 32768-bit mask of forced priors
    __shared__ int hist[256 * HCOL];            // 33 KB column-per-lane histogram
    __shared__ int total[256];
    __shared__ float rs[16];
    __shared__ int rc2[16];
    __shared__ float sh_sl1, sh_cep;
    __shared__ int sh_np, sh_k, sh_kk;
    __shared__ u32 sh_prefix;

    if (tid < NO * 5) {
        int o = tid / 5, c = tid % 5;
        float v = targets[b * NO * 5 + tid];
        if (c < 4) ((float*)&tbc[o])[c] = v; else tlab[o] = v;
    }
    flags[tid] = 0u;
    for (int i = tid; i < 256 * HCOL; i += 1024) hist[i] = 0;

    const float* mb = mine + (size_t)b * NP;
    float v[32];
#pragma unroll
    for (int q = 0; q < 8; ++q) {
        float4 t4 = ((const float4*)mb)[q * 1024 + tid];
        v[4 * q] = t4.x; v[4 * q + 1] = t4.y; v[4 * q + 2] = t4.z; v[4 * q + 3] = t4.w;
    }
    __syncthreads();
    // ---- pass-0 histogram on PRE-fix values (corrections applied in fix phase) ----
#pragma unroll 8
    for (int j = 0; j < 32; ++j)
        atomicAdd(&hist[(__float_as_uint(v[j]) >> 24) * HCOL + cl], 1);
    if (tid < NO) {
        float4 t = tbc[tid];
        tas[tid] = (t.z - t.x) * (t.w - t.y);
        // resolve per-truth best prior across the 64 x-tiles
        u64 key = 0ull;
        for (int xx = 0; xx < NT1; ++xx) {
            u64 t2 = bpk_part[(b * NT1 + xx) * 32 + tid];
            key = t2 > key ? t2 : key;
        }
        pp[tid] = (key >> 32) ? ~(u32)key : 0u;   // all-zero row => argmax = 0
    }
    __syncthreads();
    if (tid < NO) {
        const int o = tid;
        const u32 p = pp[o];
        float dsl1 = 0.f, dcep = 0.f; int dnp = 0;
        bool last = true;
        for (int o2 = o + 1; o2 < NO; ++o2)
            if (pp[o2] == p) { last = false; break; }   // later o overwrites same prior
        if (last) {
            float4 prr = ((const float4*)priors)[p];
            float px1 = prr.x - prr.z * 0.5f, py1 = prr.y - prr.w * 0.5f;
            float px2 = prr.x + prr.z * 0.5f, py2 = prr.y + prr.w * 0.5f;
            float ab = prr.z * prr.w;
            // pre-fix best truth for p (natural order, strict > == first-max)
            float bv = -1.f; int bo_ = 0;
            for (int o2 = 0; o2 < NO; ++o2) {
                float4 t2 = tbc[o2];
                float i2 = iou_corners(px1, py1, px2, py2, ab, t2.x, t2.y, t2.z, t2.w, tas[o2]);
                if (i2 > bv) { bv = i2; bo_ = o2; }
            }
            int cf_pre = (bv < THRESH) ? 0 : ((int)tlab[bo_] + 1);
            size_t gp = (size_t)b * NP + p;
            float4 ld = ((const float4*)loc)[gp];
            float2 c = ((const float2*)conf)[gp];
            float lse = lse2(c.x, c.y);
            int cf_new = (int)tlab[o] + 1;               // forced positive
            dsl1 = smooth_l1_sum(ld, prr, tbc[o]);
            dcep = lse - ((cf_new == 0) ? c.x : c.y);
            dnp = 1;
            if (cf_pre > 0) {                            // remove pre-fix contribution
                dsl1 -= smooth_l1_sum(ld, prr, tbc[bo_]);
                dcep -= lse - ((cf_pre == 0) ? c.x : c.y);
                dnp = 0;
            }
            // pass-0 histogram correction: old value leaves its bin, 0.0 enters bin 0
            float oldv = mb[p];
            atomicSub(&hist[(__float_as_uint(oldv) >> 24) * HCOL + cl], 1);
            atomicAdd(&hist[cl], 1);
            atomicOr(&flags[p >> 5], 1u << (p & 31));
        }
        // batch stats: 64 kern1 partials + this lane's delta
        float a = part_sl1[b * NT1 + o] + part_sl1[b * NT1 + 32 + o] + dsl1;
        float d = part_cep[b * NT1 + o] + part_cep[b * NT1 + 32 + o] + dcep;
        int   n = part_np [b * NT1 + o] + part_np [b * NT1 + 32 + o] + dnp;
#pragma unroll
        for (int m = 16; m; m >>= 1) {
            a += __shfl_xor(a, m, 32);
            d += __shfl_xor(d, m, 32);
            n += __shfl_xor(n, m, 32);
        }
        if (o == 0) {
            sh_sl1 = a; sh_cep = d; sh_np = n;
            sh_k = min(7 * n, NP - 1); sh_kk = sh_k; sh_prefix = 0u;
        }
    }
    __syncthreads();
    // zero forced priors in-register (they become pos => mine 0)
#pragma unroll
    for (int q = 0; q < 8; ++q) {
        u32 word = flags[q * 128 + (tid >> 3)];
#pragma unroll
        for (int c = 0; c < 4; ++c)
            if ((word >> (((tid & 7) << 2) + c)) & 1u) v[4 * q + c] = 0.f;
    }
    const int k = sh_k;
    float topk = 0.f;
    if (k > 0) {
        for (int pass = 0; pass < 4; ++pass) {
            if (pass > 0) {                       // pass 0's hist was built above
                for (int i = tid; i < 256 * HCOL; i += 1024) hist[i] = 0;
                __syncthreads();
                const int shift = 24 - 8 * pass;
                const u32 pfx = sh_prefix;
#pragma unroll 8
                for (int j = 0; j < 32; ++j) {
                    u32 kb = __float_as_uint(v[j]);
                    if ((u32)(((u64)kb) >> (shift + 8)) == pfx)   // 64-bit shift: defined at 32
                        atomicAdd(&hist[((kb >> shift) & 255) * HCOL + cl], 1);
                }
                __syncthreads();
            }
            if (tid < 512) {   // reduce 32 columns/bin: 2 threads per bin, 16 each
                int bin = tid >> 1;
                const int base = bin * HCOL + (tid & 1) * 16;
                int s = 0;
#pragma unroll
                for (int i = 0; i < 16; ++i) s += hist[base + i];
                s += __shfl_xor(s, 1, 64);
                if ((tid & 1) == 0) total[bin] = s;
            }
            __syncthreads();
            if (tid < 64) {                  // suffix-scan select over 256 bins
                int4 h4 = ((const int4*)total)[tid];
                int s3 = h4.w, s2 = h4.z + s3, s1 = h4.y + s2, s0 = h4.x + s1;
                int acc = s0;
#pragma unroll
                for (int off = 1; off < 64; off <<= 1) {
                    int u = __shfl_down(acc, off, 64);
                    if (tid + off < 64) acc += u;
                }
                int excl = acc - s0;
                int kk = sh_kk;
                int cand = -1, nkk = 0;
                if (excl + s3 >= kk)      { cand = 4 * tid + 3; nkk = kk - excl; }
                else if (excl + s2 >= kk) { cand = 4 * tid + 2; nkk = kk - excl - s3; }
                else if (excl + s1 >= kk) { cand = 4 * tid + 1; nkk = kk - excl - s2; }
                else if (excl + s0 >= kk) { cand = 4 * tid + 0; nkk = kk - excl - s1; }
                int cmax = cand;
#pragma unroll
                for (int off = 1; off < 64; off <<= 1) cmax = max(cmax, __shfl_xor(cmax, off, 64));
                if (cand >= 0 && cand == cmax) {
                    sh_prefix = (sh_prefix << 8) | (u32)(cand & 255);
                    sh_kk = nkk;
                }
            }
            __syncthreads();
        }
        const u32 T = sh_prefix;                // exact k-th largest key
        const float tval = __uint_as_float(T);
        float s = 0.f; int c2 = 0;
#pragma unroll
        for (int j = 0; j < 32; ++j) {
            if (__float_as_uint(v[j]) > T) { s += v[j]; c2++; }
        }
#pragma unroll
        for (int m = 32; m; m >>= 1) {
            s  += __shfl_xor(s, m, 64);
            c2 += __shfl_xor(c2, m, 64);
        }
        if (lane == 0) { rs[wave] = s; rc2[wave] = c2; }
        __syncthreads();
        if (tid == 0) {
            float st = 0.f; int ct = 0;
            for (int i = 0; i < 16; ++i) { st += rs[i]; ct += rc2[i]; }
            topk = st + (float)(k - ct) * tval; // ties at T fill remaining slots
        }
    }
    if (tid == 0) {                            // accumulate + last-block finalize
        atomicAdd(sl_tot, sh_sl1);
        atomicAdd(c_tot, sh_cep + topk);
        atomicAdd(np_tot, sh_np);
        __threadfence();
        int d = atomicAdd(done_cnt, 1);
        if (d == NB - 1) {
            float sl = atomicAdd(sl_tot, 0.f);   // coherent reads incl. all contributions
            float cc = atomicAdd(c_tot, 0.f);
            int   np = atomicAdd(np_tot, 0);
            float N = fmaxf((float)np, 1.f);
            out[0] = sl / N;
            out[1] = cc / N;
        }
    }
}

extern "C" void kernel_launch(void* const* d_in, const int* in_sizes, int n_in,
                              void* d_out, int out_size, void* d_ws, size_t ws_size,
                              hipStream_t stream) {
    const float* loc     = (const float*)d_in[0];   // (B,P,4)
    const float* conf    = (const float*)d_in[1];   // (B,P,2)
    const float* priors  = (const float*)d_in[2];   // (P,4)
    const float* targets = (const float*)d_in[3];   // (B,O,5)
    float* out = (float*)d_out;

    char* ws = (char*)d_ws;
    float* mine     = (float*)ws;                       // 4 MB, fully written by K1
    u64*   bpk_part = (u64*)(ws + 4194304);             // 512 KB [b][64][32], fully written by K1
    float* part_sl1 = (float*)(ws + 4718592);           // [b][64] kern1 partials (8 KB each)
    float* part_cep = (float*)(ws + 4726784);
    int*   part_np  = (int*)(ws + 4734976);
    float* sl_tot   = (float*)(ws + 4743168);           // zero-inited by kern1 block (0,0)
    float* c_tot    = (float*)(ws + 4743172);
    int*   np_tot   = (int*)(ws + 4743176);
    int*   done_cnt = (int*)(ws + 4743180);

    dim3 g1(NT1, NB);
    kern1<<<g1, 256, 0, stream>>>(loc, conf, priors, targets, mine, bpk_part,
                                  part_sl1, part_cep, part_np,
                                  sl_tot, c_tot, np_tot, done_cnt);
    kern3<<<NB, 1024, 0, stream>>>(loc, conf, priors, targets, bpk_part, mine,
                                   part_sl1, part_cep, part_np,
                                   sl_tot, c_tot, np_tot, done_cnt, out);
}